// Round 10
// baseline (102.728 us; speedup 1.0000x reference)
//
#include <hip/hip_runtime.h>
#include <hip/hip_bf16.h>

#define H 256
#define SEQ 10
#define C2LOG2E 2.8853900817779268f   // 2*log2(e)
#define LOG2E 1.4426950408889634f

typedef __attribute__((ext_vector_type(8))) short bf16x8;
typedef __attribute__((ext_vector_type(4))) float f32x4;

__device__ __forceinline__ unsigned short f2bf(float x) {
    union { float f; unsigned u; } v; v.f = x;
    unsigned r = v.u + 0x7fff + ((v.u >> 16) & 1);  // RNE
    return (unsigned short)(r >> 16);
}
__device__ __forceinline__ float bf2f(unsigned short b) {
    union { unsigned u; float f; } v; v.u = ((unsigned)b) << 16;
    return v.f;
}
__device__ __forceinline__ float fexp2(float x) {
    return __builtin_amdgcn_exp2f(x);
}

// Merged: blocks [0, nWt) build Wt (pre-scaled by 2*log2e, transposed);
// blocks [nWt, ...) build seg_start.
__global__ void prep_kernel(const float* __restrict__ W,
                            unsigned short* __restrict__ Wt,
                            const int* __restrict__ seg_ids,
                            int* __restrict__ seg_start,
                            int nWt, int n, int num_seg) {
    if ((int)blockIdx.x < nWt) {
        int idx = blockIdx.x * 256 + threadIdx.x;
        if (idx >= H * 3 * H) return;
        int nn = idx / (3 * H), k = idx % (3 * H);
        Wt[idx] = f2bf(C2LOG2E * W[k * H + nn]);
    } else {
        int j = (blockIdx.x - nWt) * 256 + threadIdx.x;
        if (j >= n) return;
        int cur = seg_ids[j];
        int prev = (j == 0) ? -1 : seg_ids[j - 1];
        for (int s2 = prev + 1; s2 <= cur; s2++) seg_start[s2] = j;
        if (j == n - 1)
            for (int s2 = cur + 1; s2 <= num_seg; s2++) seg_start[s2] = n;
    }
}

// Merged tiled bf16 MFMA GEMM, tile 64(m) x 256(n), 4 waves.
// Blocks [0, nEntBlk): ent_proj  (A = f32 ent_embeds rows, K=256, k0=0,
//   out=comb stride 512; staged bf16 A also written to comb em half).
// Blocks [nEntBlk, ..): qpart    (A row m = [ent[s[m]]|rel[r[m]]], K=512,
//   k0=256, out=qpart stride 256, bias added).
__global__ void gemm_bf16_kernel(const float* __restrict__ entf,
                                 const int* __restrict__ sidx,
                                 const int* __restrict__ ridx,
                                 const float* __restrict__ rel,
                                 const unsigned short* __restrict__ Wt,
                                 const float* __restrict__ bias,
                                 unsigned short* __restrict__ comb,
                                 unsigned short* __restrict__ qpart,
                                 int nEntBlk, int M0, int M1) {
    __shared__ unsigned short As[64][40];
    __shared__ unsigned short Bs[256][40];
    bool isEnt = (int)blockIdx.x < nEntBlk;
    int m0 = (isEnt ? blockIdx.x : (blockIdx.x - nEntBlk)) * 64;
    int M = isEnt ? M0 : M1;
    int K = isEnt ? H : 2 * H;
    int k0 = isEnt ? 0 : H;
    int ldo = isEnt ? 512 : H;
    unsigned short* outp = isEnt ? comb : qpart;

    int t = threadIdx.x;
    int sr = t >> 2;          // 0..63
    int sc = (t & 3) * 8;     // 0/8/16/24
    int wave = t >> 6, lane = t & 63;
    int lr = lane & 15, lg = lane >> 4;

    f32x4 acc[4][4];
#pragma unroll
    for (int i = 0; i < 4; i++)
#pragma unroll
        for (int jn = 0; jn < 4; jn++) acc[i][jn] = (f32x4){0.f, 0.f, 0.f, 0.f};

    for (int kk = 0; kk < K; kk += 32) {
        bf16x8 av = {};
        int gm = m0 + sr;
        if (gm < M) {
            const float* src;
            if (isEnt) {
                src = entf + (size_t)gm * H + kk + sc;
            } else {
                int k = kk + sc;
                src = (k < H) ? (entf + (size_t)sidx[gm] * H + k)
                              : (rel + (size_t)ridx[gm] * H + (k - H));
            }
            float4 f0 = *reinterpret_cast<const float4*>(src);
            float4 f1 = *reinterpret_cast<const float4*>(src + 4);
            av[0] = (short)f2bf(f0.x); av[1] = (short)f2bf(f0.y);
            av[2] = (short)f2bf(f0.z); av[3] = (short)f2bf(f0.w);
            av[4] = (short)f2bf(f1.x); av[5] = (short)f2bf(f1.y);
            av[6] = (short)f2bf(f1.z); av[7] = (short)f2bf(f1.w);
            if (isEnt)
                *reinterpret_cast<bf16x8*>(comb + (size_t)gm * 512 + 256 + kk + sc) = av;
        }
        *reinterpret_cast<bf16x8*>(&As[sr][sc]) = av;
#pragma unroll
        for (int r4 = 0; r4 < 4; r4++) {
            int row = r4 * 64 + sr;
            bf16x8 bv = *reinterpret_cast<const bf16x8*>(
                Wt + (size_t)row * (3 * H) + k0 + kk + sc);
            *reinterpret_cast<bf16x8*>(&Bs[row][sc]) = bv;
        }
        __syncthreads();

        bf16x8 afr[4], bfr[4];
#pragma unroll
        for (int am = 0; am < 4; am++)
            afr[am] = *reinterpret_cast<const bf16x8*>(&As[am * 16 + lr][lg * 8]);
#pragma unroll
        for (int bn = 0; bn < 4; bn++)
            bfr[bn] = *reinterpret_cast<const bf16x8*>(&Bs[wave * 64 + bn * 16 + lr][lg * 8]);
#pragma unroll
        for (int am = 0; am < 4; am++)
#pragma unroll
            for (int bn = 0; bn < 4; bn++)
                acc[am][bn] = __builtin_amdgcn_mfma_f32_16x16x32_bf16(
                    afr[am], bfr[bn], acc[am][bn], 0, 0, 0);
        __syncthreads();
    }

#pragma unroll
    for (int bn = 0; bn < 4; bn++) {
        int col = wave * 64 + bn * 16 + lr;
        float bv = isEnt ? 0.f : C2LOG2E * bias[col];
#pragma unroll
        for (int am = 0; am < 4; am++) {
#pragma unroll
            for (int rr = 0; rr < 4; rr++) {
                int row = m0 + am * 16 + lg * 4 + rr;
                if (row < M)
                    outp[(size_t)row * ldo + col] = f2bf(acc[am][bn][rr] + bv);
            }
        }
    }
}

// Persistent waves, static interleaved segment assignment (seg = wid + k*nw).
// 2x-unrolled neighbor loop: each lane-group keeps TWO independent neighbors
// in flight (8/wave/iter) so the serial score->shfl->exp2 chains of the two
// overlap. Single pass, no max-subtraction (|score| <= ~10.2).
// proj & qpart pre-scaled by 2*log2e: tanh = 1 - 2*rcp(exp2(p'+q')+1);
// score = sum(v) - 2*sum(v*r).
// launch_bounds(256,3): VGPR cap 170 — natural ~105, headroom against spill
// ((256,6) forced 40 VGPRs -> spilled, +128MB scratch, 4x slower).
__global__ void __launch_bounds__(256, 3)
fused_agg_kernel(const int* __restrict__ nbr_ids,
                 const int* __restrict__ seg_start,
                 const unsigned short* __restrict__ comb,
                 const unsigned short* __restrict__ qpartbf,
                 const float* __restrict__ v_s,
                 const float* __restrict__ ent_embeds,
                 const float* __restrict__ rel_embeds,
                 const int* __restrict__ s,
                 const int* __restrict__ r,
                 float* __restrict__ out, int num_seg) {
    int wid = blockIdx.x * 4 + (threadIdx.x >> 6);
    int nw = gridDim.x * 4;
    int lane = threadIdx.x & 63;
    int g = lane >> 4, li = lane & 15;
    int cb = li * 16;
    int c4 = lane * 4;

    // hoisted: v columns for this lane
    float vm2[16];  // -2*v
    float vsum = 0.f;
    {
        const float4* vp = reinterpret_cast<const float4*>(v_s + cb);
#pragma unroll
        for (int k = 0; k < 4; k++) {
            float4 tv = vp[k];
            vm2[4 * k + 0] = -2.f * tv.x; vm2[4 * k + 1] = -2.f * tv.y;
            vm2[4 * k + 2] = -2.f * tv.z; vm2[4 * k + 3] = -2.f * tv.w;
            vsum += tv.x + tv.y + tv.z + tv.w;
        }
    }

    for (int seg = wid; seg < num_seg; seg += nw) {
        int start = seg_start[seg], end = seg_start[seg + 1];
        int b = seg / SEQ;
        float* orow = out + (size_t)seg * (3 * H);

        if (start == end) {
            float4 z = {0.f, 0.f, 0.f, 0.f};
            *reinterpret_cast<float4*>(orow + c4) = z;
            *reinterpret_cast<float4*>(orow + H + c4) = z;
            *reinterpret_cast<float4*>(orow + 2 * H + c4) = z;
            continue;
        }

        float qv[16];
        {
            bf16x8 qa = *reinterpret_cast<const bf16x8*>(qpartbf + (size_t)b * H + cb);
            bf16x8 qb = *reinterpret_cast<const bf16x8*>(qpartbf + (size_t)b * H + cb + 8);
#pragma unroll
            for (int k = 0; k < 8; k++) {
                qv[k] = bf2f((unsigned short)qa[k]);
                qv[8 + k] = bf2f((unsigned short)qb[k]);
            }
        }

        float acc[16];
#pragma unroll
        for (int k = 0; k < 16; k++) acc[k] = 0.f;
        float lpart = 0.f;

        int cc = end - start;
        int nitm = (cc + 7) >> 3;   // 8 neighbors per iteration (2 per group)

        int jA = min(g, cc - 1);
        int jB = min(4 + g, cc - 1);
        const unsigned short* rowA = comb + (size_t)nbr_ids[start + jA] * 512 + cb;
        const unsigned short* rowB = comb + (size_t)nbr_ids[start + jB] * 512 + cb;
        bf16x8 pA0 = *reinterpret_cast<const bf16x8*>(rowA);
        bf16x8 pA1 = *reinterpret_cast<const bf16x8*>(rowA + 8);
        bf16x8 pB0 = *reinterpret_cast<const bf16x8*>(rowB);
        bf16x8 pB1 = *reinterpret_cast<const bf16x8*>(rowB + 8);

        for (int ji = 0; ji < nitm; ji++) {
            // em loads for the two current neighbors
            bf16x8 eA0 = *reinterpret_cast<const bf16x8*>(rowA + 256);
            bf16x8 eA1 = *reinterpret_cast<const bf16x8*>(rowA + 264);
            bf16x8 eB0 = *reinterpret_cast<const bf16x8*>(rowB + 256);
            bf16x8 eB1 = *reinterpret_cast<const bf16x8*>(rowB + 264);
            // prefetch next pair's proj
            int jAn = min(8 * (ji + 1) + g, cc - 1);
            int jBn = min(8 * (ji + 1) + 4 + g, cc - 1);
            const unsigned short* rowAn = comb + (size_t)nbr_ids[start + jAn] * 512 + cb;
            const unsigned short* rowBn = comb + (size_t)nbr_ids[start + jBn] * 512 + cb;
            bf16x8 pA0n = *reinterpret_cast<const bf16x8*>(rowAn);
            bf16x8 pA1n = *reinterpret_cast<const bf16x8*>(rowAn + 8);
            bf16x8 pB0n = *reinterpret_cast<const bf16x8*>(rowBn);
            bf16x8 pB1n = *reinterpret_cast<const bf16x8*>(rowBn + 8);

            // two independent score chains
            float sA = 0.f, sB = 0.f;
#pragma unroll
            for (int k = 0; k < 8; k++) {
                sA = fmaf(vm2[k], __builtin_amdgcn_rcpf(
                         fexp2(bf2f((unsigned short)pA0[k]) + qv[k]) + 1.f), sA);
                sB = fmaf(vm2[k], __builtin_amdgcn_rcpf(
                         fexp2(bf2f((unsigned short)pB0[k]) + qv[k]) + 1.f), sB);
                sA = fmaf(vm2[8 + k], __builtin_amdgcn_rcpf(
                         fexp2(bf2f((unsigned short)pA1[k]) + qv[8 + k]) + 1.f), sA);
                sB = fmaf(vm2[8 + k], __builtin_amdgcn_rcpf(
                         fexp2(bf2f((unsigned short)pB1[k]) + qv[8 + k]) + 1.f), sB);
            }
            sA += vsum; sB += vsum;
            // interleaved shfl chains (latencies overlap)
            sA += __shfl_xor(sA, 1);  sB += __shfl_xor(sB, 1);
            sA += __shfl_xor(sA, 2);  sB += __shfl_xor(sB, 2);
            sA += __shfl_xor(sA, 4);  sB += __shfl_xor(sB, 4);
            sA += __shfl_xor(sA, 8);  sB += __shfl_xor(sB, 8);
            float eA = fexp2(sA * LOG2E);
            float eB = fexp2(sB * LOG2E);
            eA = (8 * ji + g < cc) ? eA : 0.f;
            eB = (8 * ji + 4 + g < cc) ? eB : 0.f;
            lpart += eA + eB;
#pragma unroll
            for (int k = 0; k < 8; k++) {
                acc[k]     = fmaf(eA, bf2f((unsigned short)eA0[k]), acc[k]);
                acc[k]     = fmaf(eB, bf2f((unsigned short)eB0[k]), acc[k]);
                acc[8 + k] = fmaf(eA, bf2f((unsigned short)eA1[k]), acc[8 + k]);
                acc[8 + k] = fmaf(eB, bf2f((unsigned short)eB1[k]), acc[8 + k]);
            }
            pA0 = pA0n; pA1 = pA1n; pB0 = pB0n; pB1 = pB1n;
            rowA = rowAn; rowB = rowBn;
        }

        lpart += __shfl_xor(lpart, 16);
        lpart += __shfl_xor(lpart, 32);
#pragma unroll
        for (int k = 0; k < 16; k++) {
            acc[k] += __shfl_xor(acc[k], 16);
            acc[k] += __shfl_xor(acc[k], 32);
        }
        float invl = 1.f / lpart;

        float4 o;
#pragma unroll
        for (int k = 0; k < 4; k++) {
            float v0 = acc[k], v1 = acc[4 + k], v2 = acc[8 + k], v3 = acc[12 + k];
            float pick = (g == 0) ? v0 : (g == 1) ? v1 : (g == 2) ? v2 : v3;
            if (k == 0) o.x = pick * invl;
            else if (k == 1) o.y = pick * invl;
            else if (k == 2) o.z = pick * invl;
            else o.w = pick * invl;
        }
        *reinterpret_cast<float4*>(orow + cb + 4 * g) = o;
        *reinterpret_cast<float4*>(orow + H + c4) =
            *reinterpret_cast<const float4*>(ent_embeds + (size_t)s[b] * H + c4);
        *reinterpret_cast<float4*>(orow + 2 * H + c4) =
            *reinterpret_cast<const float4*>(rel_embeds + (size_t)r[b] * H + c4);
    }
}

extern "C" void kernel_launch(void* const* d_in, const int* in_sizes, int n_in,
                              void* d_out, int out_size, void* d_ws, size_t ws_size,
                              hipStream_t stream) {
    const int* s = (const int*)d_in[0];
    const int* r = (const int*)d_in[1];
    const int* nbr_ids = (const int*)d_in[2];
    const int* seg_ids = (const int*)d_in[3];
    const float* ent_embeds = (const float*)d_in[4];
    const float* rel_embeds = (const float*)d_in[5];
    const float* W_attn = (const float*)d_in[6];
    const float* b_attn = (const float*)d_in[7];
    const float* v_s = (const float*)d_in[8];
    float* out = (float*)d_out;

    int B = in_sizes[0];
    int N = in_sizes[2];
    int num_ent = in_sizes[4] / H;
    int num_seg = B * SEQ;

    char* ws = (char*)d_ws;
    unsigned short* comb = (unsigned short*)ws;                 // num_ent*512 (proj'|em)
    unsigned short* Wt = comb + (size_t)num_ent * 512;          // H*3H (pre-scaled)
    unsigned short* qpartbf = Wt + (size_t)H * 3 * H;           // B*H (pre-scaled)
    int* seg_start = (int*)(qpartbf + (size_t)B * H);           // num_seg+1

    int nWt = (H * 3 * H + 255) / 256;       // 768
    int nSeg = (N + 255) / 256;              // 1280
    prep_kernel<<<nWt + nSeg, 256, 0, stream>>>(W_attn, Wt, seg_ids, seg_start,
                                                nWt, N, num_seg);

    int nEntBlk = (num_ent + 63) / 64;       // 313
    int nQBlk = B / 64;                      // 32
    gemm_bf16_kernel<<<nEntBlk + nQBlk, 256, 0, stream>>>(
        ent_embeds, s, r, rel_embeds, Wt, b_attn, comb, qpartbf,
        nEntBlk, num_ent, B);

    fused_agg_kernel<<<2048, 256, 0, stream>>>(
        nbr_ids, seg_start, comb, qpartbf, v_s,
        ent_embeds, rel_embeds, s, r, out, num_seg);
}

// Round 11
// 93.702 us; speedup vs baseline: 1.0963x; 1.0963x over previous
//
#include <hip/hip_runtime.h>
#include <hip/hip_bf16.h>

#define H 256
#define SEQ 10
#define C2LOG2E 2.8853900817779268f   // 2*log2(e)
#define LOG2E 1.4426950408889634f

typedef __attribute__((ext_vector_type(8))) short bf16x8;
typedef __attribute__((ext_vector_type(4))) float f32x4;

__device__ __forceinline__ unsigned short f2bf(float x) {
    union { float f; unsigned u; } v; v.f = x;
    unsigned r = v.u + 0x7fff + ((v.u >> 16) & 1);  // RNE
    return (unsigned short)(r >> 16);
}
__device__ __forceinline__ float bf2f(unsigned short b) {
    union { unsigned u; float f; } v; v.u = ((unsigned)b) << 16;
    return v.f;
}
__device__ __forceinline__ float fexp2(float x) {
    return __builtin_amdgcn_exp2f(x);
}

// Merged: blocks [0, nWt) build Wt (pre-scaled by 2*log2e, transposed);
// blocks [nWt, ...) build seg_start.
__global__ void prep_kernel(const float* __restrict__ W,
                            unsigned short* __restrict__ Wt,
                            const int* __restrict__ seg_ids,
                            int* __restrict__ seg_start,
                            int nWt, int n, int num_seg) {
    if ((int)blockIdx.x < nWt) {
        int idx = blockIdx.x * 256 + threadIdx.x;
        if (idx >= H * 3 * H) return;
        int nn = idx / (3 * H), k = idx % (3 * H);
        Wt[idx] = f2bf(C2LOG2E * W[k * H + nn]);
    } else {
        int j = (blockIdx.x - nWt) * 256 + threadIdx.x;
        if (j >= n) return;
        int cur = seg_ids[j];
        int prev = (j == 0) ? -1 : seg_ids[j - 1];
        for (int s2 = prev + 1; s2 <= cur; s2++) seg_start[s2] = j;
        if (j == n - 1)
            for (int s2 = cur + 1; s2 <= num_seg; s2++) seg_start[s2] = n;
    }
}

// Merged tiled bf16 MFMA GEMM, tile 64(m) x 256(n), 4 waves.
// A staged via LDS (f32->bf16 conversion shared across waves); B (Wt rows,
// contiguous in k, L2-hot across all blocks) loaded DIRECT to registers —
// no Bs LDS staging (saves 8 LDS ops/thread/k-step, LDS 25KB->5KB).
// Blocks [0, nEntBlk): ent_proj  (out=comb stride 512; staged bf16 A also
//   written to comb em half).  Blocks [nEntBlk, ..): qpart (+bias).
__global__ void gemm_bf16_kernel(const float* __restrict__ entf,
                                 const int* __restrict__ sidx,
                                 const int* __restrict__ ridx,
                                 const float* __restrict__ rel,
                                 const unsigned short* __restrict__ Wt,
                                 const float* __restrict__ bias,
                                 unsigned short* __restrict__ comb,
                                 unsigned short* __restrict__ qpart,
                                 int nEntBlk, int M0, int M1) {
    __shared__ unsigned short As[64][40];
    bool isEnt = (int)blockIdx.x < nEntBlk;
    int m0 = (isEnt ? blockIdx.x : (blockIdx.x - nEntBlk)) * 64;
    int M = isEnt ? M0 : M1;
    int K = isEnt ? H : 2 * H;
    int k0 = isEnt ? 0 : H;
    int ldo = isEnt ? 512 : H;
    unsigned short* outp = isEnt ? comb : qpart;

    int t = threadIdx.x;
    int sr = t >> 2;          // 0..63
    int sc = (t & 3) * 8;     // 0/8/16/24
    int wave = t >> 6, lane = t & 63;
    int lr = lane & 15, lg = lane >> 4;

    f32x4 acc[4][4];
#pragma unroll
    for (int i = 0; i < 4; i++)
#pragma unroll
        for (int jn = 0; jn < 4; jn++) acc[i][jn] = (f32x4){0.f, 0.f, 0.f, 0.f};

    // per-lane B row pointers (4 fragments, fixed rows, k advances)
    const unsigned short* bp[4];
#pragma unroll
    for (int bn = 0; bn < 4; bn++)
        bp[bn] = Wt + (size_t)(wave * 64 + bn * 16 + lr) * (3 * H) + k0 + lg * 8;

    for (int kk = 0; kk < K; kk += 32) {
        bf16x8 av = {};
        int gm = m0 + sr;
        if (gm < M) {
            const float* src;
            if (isEnt) {
                src = entf + (size_t)gm * H + kk + sc;
            } else {
                int k = kk + sc;
                src = (k < H) ? (entf + (size_t)sidx[gm] * H + k)
                              : (rel + (size_t)ridx[gm] * H + (k - H));
            }
            float4 f0 = *reinterpret_cast<const float4*>(src);
            float4 f1 = *reinterpret_cast<const float4*>(src + 4);
            av[0] = (short)f2bf(f0.x); av[1] = (short)f2bf(f0.y);
            av[2] = (short)f2bf(f0.z); av[3] = (short)f2bf(f0.w);
            av[4] = (short)f2bf(f1.x); av[5] = (short)f2bf(f1.y);
            av[6] = (short)f2bf(f1.z); av[7] = (short)f2bf(f1.w);
            if (isEnt)
                *reinterpret_cast<bf16x8*>(comb + (size_t)gm * 512 + 256 + kk + sc) = av;
        }
        *reinterpret_cast<bf16x8*>(&As[sr][sc]) = av;

        // B fragments direct from global (L2-hot)
        bf16x8 bfr[4];
#pragma unroll
        for (int bn = 0; bn < 4; bn++)
            bfr[bn] = *reinterpret_cast<const bf16x8*>(bp[bn] + kk);

        __syncthreads();
        bf16x8 afr[4];
#pragma unroll
        for (int am = 0; am < 4; am++)
            afr[am] = *reinterpret_cast<const bf16x8*>(&As[am * 16 + lr][lg * 8]);
#pragma unroll
        for (int am = 0; am < 4; am++)
#pragma unroll
            for (int bn = 0; bn < 4; bn++)
                acc[am][bn] = __builtin_amdgcn_mfma_f32_16x16x32_bf16(
                    afr[am], bfr[bn], acc[am][bn], 0, 0, 0);
        __syncthreads();
    }

#pragma unroll
    for (int bn = 0; bn < 4; bn++) {
        int col = wave * 64 + bn * 16 + lr;
        float bv = isEnt ? 0.f : C2LOG2E * bias[col];
#pragma unroll
        for (int am = 0; am < 4; am++) {
#pragma unroll
            for (int rr = 0; rr < 4; rr++) {
                int row = m0 + am * 16 + lg * 4 + rr;
                if (row < M)
                    outp[(size_t)row * ldo + col] = f2bf(acc[am][bn][rr] + bv);
            }
        }
    }
}

// Persistent waves, static interleaved segment assignment (seg = wid + k*nw).
// Lane group g (16 lanes) handles neighbors j == 4*ji+g; lane covers 16 cols.
// Fully 1-deep software pipeline: next row's proj AND em loaded each iter,
// current held in regs (~full-iteration latency cover). Score reduction uses
// two partial sums (8-deep chains instead of 16). Single pass, no
// max-subtraction (|score| <= ~10.2). proj & qpart pre-scaled by 2*log2e:
// tanh = 1 - 2*rcp(exp2(p'+q')+1); score = sum(v) - 2*sum(v*r).
// launch_bounds(256,4): VGPR cap 128 — natural ~75, NO spill
// ((256,6) forced 40 VGPRs -> spilled, +128MB scratch, 4x slower).
__global__ void __launch_bounds__(256, 4)
fused_agg_kernel(const int* __restrict__ nbr_ids,
                 const int* __restrict__ seg_start,
                 const unsigned short* __restrict__ comb,
                 const unsigned short* __restrict__ qpartbf,
                 const float* __restrict__ v_s,
                 const float* __restrict__ ent_embeds,
                 const float* __restrict__ rel_embeds,
                 const int* __restrict__ s,
                 const int* __restrict__ r,
                 float* __restrict__ out, int num_seg) {
    int wid = blockIdx.x * 4 + (threadIdx.x >> 6);
    int nw = gridDim.x * 4;
    int lane = threadIdx.x & 63;
    int g = lane >> 4, li = lane & 15;
    int cb = li * 16;
    int c4 = lane * 4;

    // hoisted: v columns for this lane
    float vm2[16];  // -2*v
    float vsum = 0.f;
    {
        const float4* vp = reinterpret_cast<const float4*>(v_s + cb);
#pragma unroll
        for (int k = 0; k < 4; k++) {
            float4 tv = vp[k];
            vm2[4 * k + 0] = -2.f * tv.x; vm2[4 * k + 1] = -2.f * tv.y;
            vm2[4 * k + 2] = -2.f * tv.z; vm2[4 * k + 3] = -2.f * tv.w;
            vsum += tv.x + tv.y + tv.z + tv.w;
        }
    }

    for (int seg = wid; seg < num_seg; seg += nw) {
        int start = seg_start[seg], end = seg_start[seg + 1];
        int b = seg / SEQ;
        float* orow = out + (size_t)seg * (3 * H);

        if (start == end) {
            float4 z = {0.f, 0.f, 0.f, 0.f};
            *reinterpret_cast<float4*>(orow + c4) = z;
            *reinterpret_cast<float4*>(orow + H + c4) = z;
            *reinterpret_cast<float4*>(orow + 2 * H + c4) = z;
            continue;
        }

        float qv[16];
        {
            bf16x8 qa = *reinterpret_cast<const bf16x8*>(qpartbf + (size_t)b * H + cb);
            bf16x8 qb = *reinterpret_cast<const bf16x8*>(qpartbf + (size_t)b * H + cb + 8);
#pragma unroll
            for (int k = 0; k < 8; k++) {
                qv[k] = bf2f((unsigned short)qa[k]);
                qv[8 + k] = bf2f((unsigned short)qb[k]);
            }
        }

        float acc[16];
#pragma unroll
        for (int k = 0; k < 16; k++) acc[k] = 0.f;
        float lpart = 0.f;

        int cc = end - start;
        int nitm = (cc + 3) >> 2;

        // prologue: load row 0's proj AND em
        int j0 = min(g, cc - 1);
        const unsigned short* row = comb + (size_t)nbr_ids[start + j0] * 512 + cb;
        bf16x8 p0 = *reinterpret_cast<const bf16x8*>(row);
        bf16x8 p1 = *reinterpret_cast<const bf16x8*>(row + 8);
        bf16x8 e0 = *reinterpret_cast<const bf16x8*>(row + 256);
        bf16x8 e1 = *reinterpret_cast<const bf16x8*>(row + 264);

        for (int ji = 0; ji < nitm; ji++) {
            // prefetch next row: proj + em (consumed next iteration)
            int jn = min(4 * (ji + 1) + g, cc - 1);
            const unsigned short* rown = comb + (size_t)nbr_ids[start + jn] * 512 + cb;
            bf16x8 p0n = *reinterpret_cast<const bf16x8*>(rown);
            bf16x8 p1n = *reinterpret_cast<const bf16x8*>(rown + 8);
            bf16x8 e0n = *reinterpret_cast<const bf16x8*>(rown + 256);
            bf16x8 e1n = *reinterpret_cast<const bf16x8*>(rown + 264);

            // two partial sums halve the dependent fma chain
            float sa = 0.f, sb = 0.f;
#pragma unroll
            for (int k = 0; k < 8; k++) {
                sa = fmaf(vm2[k], __builtin_amdgcn_rcpf(
                        fexp2(bf2f((unsigned short)p0[k]) + qv[k]) + 1.f), sa);
                sb = fmaf(vm2[8 + k], __builtin_amdgcn_rcpf(
                        fexp2(bf2f((unsigned short)p1[k]) + qv[8 + k]) + 1.f), sb);
            }
            float s16 = sa + sb + vsum;
            s16 += __shfl_xor(s16, 1);
            s16 += __shfl_xor(s16, 2);
            s16 += __shfl_xor(s16, 4);
            s16 += __shfl_xor(s16, 8);
            float e = fexp2(s16 * LOG2E);
            e = (4 * ji + g < cc) ? e : 0.f;
            lpart += e;
#pragma unroll
            for (int k = 0; k < 8; k++) {
                acc[k] = fmaf(e, bf2f((unsigned short)e0[k]), acc[k]);
                acc[8 + k] = fmaf(e, bf2f((unsigned short)e1[k]), acc[8 + k]);
            }
            p0 = p0n; p1 = p1n; e0 = e0n; e1 = e1n;
        }

        lpart += __shfl_xor(lpart, 16);
        lpart += __shfl_xor(lpart, 32);
#pragma unroll
        for (int k = 0; k < 16; k++) {
            acc[k] += __shfl_xor(acc[k], 16);
            acc[k] += __shfl_xor(acc[k], 32);
        }
        float invl = 1.f / lpart;

        float4 o;
#pragma unroll
        for (int k = 0; k < 4; k++) {
            float v0 = acc[k], v1 = acc[4 + k], v2 = acc[8 + k], v3 = acc[12 + k];
            float pick = (g == 0) ? v0 : (g == 1) ? v1 : (g == 2) ? v2 : v3;
            if (k == 0) o.x = pick * invl;
            else if (k == 1) o.y = pick * invl;
            else if (k == 2) o.z = pick * invl;
            else o.w = pick * invl;
        }
        *reinterpret_cast<float4*>(orow + cb + 4 * g) = o;
        *reinterpret_cast<float4*>(orow + H + c4) =
            *reinterpret_cast<const float4*>(ent_embeds + (size_t)s[b] * H + c4);
        *reinterpret_cast<float4*>(orow + 2 * H + c4) =
            *reinterpret_cast<const float4*>(rel_embeds + (size_t)r[b] * H + c4);
    }
}

extern "C" void kernel_launch(void* const* d_in, const int* in_sizes, int n_in,
                              void* d_out, int out_size, void* d_ws, size_t ws_size,
                              hipStream_t stream) {
    const int* s = (const int*)d_in[0];
    const int* r = (const int*)d_in[1];
    const int* nbr_ids = (const int*)d_in[2];
    const int* seg_ids = (const int*)d_in[3];
    const float* ent_embeds = (const float*)d_in[4];
    const float* rel_embeds = (const float*)d_in[5];
    const float* W_attn = (const float*)d_in[6];
    const float* b_attn = (const float*)d_in[7];
    const float* v_s = (const float*)d_in[8];
    float* out = (float*)d_out;

    int B = in_sizes[0];
    int N = in_sizes[2];
    int num_ent = in_sizes[4] / H;
    int num_seg = B * SEQ;

    char* ws = (char*)d_ws;
    unsigned short* comb = (unsigned short*)ws;                 // num_ent*512 (proj'|em)
    unsigned short* Wt = comb + (size_t)num_ent * 512;          // H*3H (pre-scaled)
    unsigned short* qpartbf = Wt + (size_t)H * 3 * H;           // B*H (pre-scaled)
    int* seg_start = (int*)(qpartbf + (size_t)B * H);           // num_seg+1

    int nWt = (H * 3 * H + 255) / 256;       // 768
    int nSeg = (N + 255) / 256;              // 1280
    prep_kernel<<<nWt + nSeg, 256, 0, stream>>>(W_attn, Wt, seg_ids, seg_start,
                                                nWt, N, num_seg);

    int nEntBlk = (num_ent + 63) / 64;       // 313
    int nQBlk = B / 64;                      // 32
    gemm_bf16_kernel<<<nEntBlk + nQBlk, 256, 0, stream>>>(
        ent_embeds, s, r, rel_embeds, Wt, b_attn, comb, qpartbf,
        nEntBlk, num_ent, B);

    fused_agg_kernel<<<2048, 256, 0, stream>>>(
        nbr_ids, seg_start, comb, qpartbf, v_s,
        ent_embeds, rel_embeds, s, r, out, num_seg);
}

// Round 12
// 91.220 us; speedup vs baseline: 1.1262x; 1.0272x over previous
//
#include <hip/hip_runtime.h>
#include <hip/hip_bf16.h>

#define H 256
#define SEQ 10
#define C2LOG2E 2.8853900817779268f   // 2*log2(e)
#define LOG2E 1.4426950408889634f

typedef __attribute__((ext_vector_type(8))) short bf16x8;
typedef __attribute__((ext_vector_type(4))) float f32x4;

__device__ __forceinline__ unsigned short f2bf(float x) {
    union { float f; unsigned u; } v; v.f = x;
    unsigned r = v.u + 0x7fff + ((v.u >> 16) & 1);  // RNE
    return (unsigned short)(r >> 16);
}
__device__ __forceinline__ float bf2f(unsigned short b) {
    union { unsigned u; float f; } v; v.u = ((unsigned)b) << 16;
    return v.f;
}
__device__ __forceinline__ float fexp2(float x) {
    return __builtin_amdgcn_exp2f(x);
}

// Merged: blocks [0, nWt) build Wt (pre-scaled by 2*log2e, transposed);
// blocks [nWt, ...) build seg_start.
__global__ void prep_kernel(const float* __restrict__ W,
                            unsigned short* __restrict__ Wt,
                            const int* __restrict__ seg_ids,
                            int* __restrict__ seg_start,
                            int nWt, int n, int num_seg) {
    if ((int)blockIdx.x < nWt) {
        int idx = blockIdx.x * 256 + threadIdx.x;
        if (idx >= H * 3 * H) return;
        int nn = idx / (3 * H), k = idx % (3 * H);
        Wt[idx] = f2bf(C2LOG2E * W[k * H + nn]);
    } else {
        int j = (blockIdx.x - nWt) * 256 + threadIdx.x;
        if (j >= n) return;
        int cur = seg_ids[j];
        int prev = (j == 0) ? -1 : seg_ids[j - 1];
        for (int s2 = prev + 1; s2 <= cur; s2++) seg_start[s2] = j;
        if (j == n - 1)
            for (int s2 = cur + 1; s2 <= num_seg; s2++) seg_start[s2] = n;
    }
}

// Merged tiled bf16 MFMA GEMM, tile 64(m) x 256(n), 4 waves.
// A staged via LDS; B (Wt rows, L2-hot) direct to registers.
// Blocks [0, nEntBlk): ent_proj  (out=comb stride 512; staged bf16 A also
//   written to comb em half).  Blocks [nEntBlk, ..): qpart (+bias).
__global__ void gemm_bf16_kernel(const float* __restrict__ entf,
                                 const int* __restrict__ sidx,
                                 const int* __restrict__ ridx,
                                 const float* __restrict__ rel,
                                 const unsigned short* __restrict__ Wt,
                                 const float* __restrict__ bias,
                                 unsigned short* __restrict__ comb,
                                 unsigned short* __restrict__ qpart,
                                 int nEntBlk, int M0, int M1) {
    __shared__ unsigned short As[64][40];
    bool isEnt = (int)blockIdx.x < nEntBlk;
    int m0 = (isEnt ? blockIdx.x : (blockIdx.x - nEntBlk)) * 64;
    int M = isEnt ? M0 : M1;
    int K = isEnt ? H : 2 * H;
    int k0 = isEnt ? 0 : H;
    int ldo = isEnt ? 512 : H;
    unsigned short* outp = isEnt ? comb : qpart;

    int t = threadIdx.x;
    int sr = t >> 2;          // 0..63
    int sc = (t & 3) * 8;     // 0/8/16/24
    int wave = t >> 6, lane = t & 63;
    int lr = lane & 15, lg = lane >> 4;

    f32x4 acc[4][4];
#pragma unroll
    for (int i = 0; i < 4; i++)
#pragma unroll
        for (int jn = 0; jn < 4; jn++) acc[i][jn] = (f32x4){0.f, 0.f, 0.f, 0.f};

    const unsigned short* bp[4];
#pragma unroll
    for (int bn = 0; bn < 4; bn++)
        bp[bn] = Wt + (size_t)(wave * 64 + bn * 16 + lr) * (3 * H) + k0 + lg * 8;

    for (int kk = 0; kk < K; kk += 32) {
        bf16x8 av = {};
        int gm = m0 + sr;
        if (gm < M) {
            const float* src;
            if (isEnt) {
                src = entf + (size_t)gm * H + kk + sc;
            } else {
                int k = kk + sc;
                src = (k < H) ? (entf + (size_t)sidx[gm] * H + k)
                              : (rel + (size_t)ridx[gm] * H + (k - H));
            }
            float4 f0 = *reinterpret_cast<const float4*>(src);
            float4 f1 = *reinterpret_cast<const float4*>(src + 4);
            av[0] = (short)f2bf(f0.x); av[1] = (short)f2bf(f0.y);
            av[2] = (short)f2bf(f0.z); av[3] = (short)f2bf(f0.w);
            av[4] = (short)f2bf(f1.x); av[5] = (short)f2bf(f1.y);
            av[6] = (short)f2bf(f1.z); av[7] = (short)f2bf(f1.w);
            if (isEnt)
                *reinterpret_cast<bf16x8*>(comb + (size_t)gm * 512 + 256 + kk + sc) = av;
        }
        *reinterpret_cast<bf16x8*>(&As[sr][sc]) = av;

        bf16x8 bfr[4];
#pragma unroll
        for (int bn = 0; bn < 4; bn++)
            bfr[bn] = *reinterpret_cast<const bf16x8*>(bp[bn] + kk);

        __syncthreads();
        bf16x8 afr[4];
#pragma unroll
        for (int am = 0; am < 4; am++)
            afr[am] = *reinterpret_cast<const bf16x8*>(&As[am * 16 + lr][lg * 8]);
#pragma unroll
        for (int am = 0; am < 4; am++)
#pragma unroll
            for (int bn = 0; bn < 4; bn++)
                acc[am][bn] = __builtin_amdgcn_mfma_f32_16x16x32_bf16(
                    afr[am], bfr[bn], acc[am][bn], 0, 0, 0);
        __syncthreads();
    }

#pragma unroll
    for (int bn = 0; bn < 4; bn++) {
        int col = wave * 64 + bn * 16 + lr;
        float bv = isEnt ? 0.f : C2LOG2E * bias[col];
#pragma unroll
        for (int am = 0; am < 4; am++) {
#pragma unroll
            for (int rr = 0; rr < 4; rr++) {
                int row = m0 + am * 16 + lg * 4 + rr;
                if (row < M)
                    outp[(size_t)row * ldo + col] = f2bf(acc[am][bn][rr] + bv);
            }
        }
    }
}

// One wave per segment, 2 waves per block (best-measured structure, r5).
// Lane group g (16 lanes) handles neighbors j == 4*ji+g; lane covers 16 cols.
// Single pass, no max-subtraction (|score| <= ~10.2).
// proj & qpart pre-scaled by 2*log2e. Paired-rcp score (exact algebra):
//   v0/(u0+1) + v1/(u1+1) = (v0*a1 + v1*a0) * rcp(a0*a1)   [a=u+1]
// -> 24 trans/neighbor-lane instead of 32. Gathers are exec-predicated
// (no clamped duplicate fetches). proj+em prefetched 1-deep; ss/rr output
// gathers issued before the loop so latency hides under it.
__global__ void __launch_bounds__(128)
fused_agg_kernel(const int* __restrict__ nbr_ids,
                 const int* __restrict__ seg_start,
                 const unsigned short* __restrict__ comb,
                 const unsigned short* __restrict__ qpartbf,
                 const float* __restrict__ v_s,
                 const float* __restrict__ ent_embeds,
                 const float* __restrict__ rel_embeds,
                 const int* __restrict__ s,
                 const int* __restrict__ r,
                 float* __restrict__ out, int num_seg) {
    int seg = blockIdx.x * 2 + (threadIdx.x >> 6);
    if (seg >= num_seg) return;
    int lane = threadIdx.x & 63;
    int g = lane >> 4, li = lane & 15;
    int cb = li * 16;
    int c4 = lane * 4;
    int b = seg / SEQ;
    int start = seg_start[seg], end = seg_start[seg + 1];
    float* orow = out + (size_t)seg * (3 * H);

    if (start == end) {
        float4 z = {0.f, 0.f, 0.f, 0.f};
        *reinterpret_cast<float4*>(orow + c4) = z;
        *reinterpret_cast<float4*>(orow + H + c4) = z;
        *reinterpret_cast<float4*>(orow + 2 * H + c4) = z;
        return;
    }

    // issue ss/rr gathers early — consumed only at the end
    float4 ssv = *reinterpret_cast<const float4*>(ent_embeds + (size_t)s[b] * H + c4);
    float4 rrv = *reinterpret_cast<const float4*>(rel_embeds + (size_t)r[b] * H + c4);

    // v columns for this lane
    float vm2[16];  // -2*v
    float vsum = 0.f;
    {
        const float4* vp = reinterpret_cast<const float4*>(v_s + cb);
#pragma unroll
        for (int k = 0; k < 4; k++) {
            float4 tv = vp[k];
            vm2[4 * k + 0] = -2.f * tv.x; vm2[4 * k + 1] = -2.f * tv.y;
            vm2[4 * k + 2] = -2.f * tv.z; vm2[4 * k + 3] = -2.f * tv.w;
            vsum += tv.x + tv.y + tv.z + tv.w;
        }
    }

    float qv[16];
    {
        bf16x8 qa = *reinterpret_cast<const bf16x8*>(qpartbf + (size_t)b * H + cb);
        bf16x8 qb = *reinterpret_cast<const bf16x8*>(qpartbf + (size_t)b * H + cb + 8);
#pragma unroll
        for (int k = 0; k < 8; k++) {
            qv[k] = bf2f((unsigned short)qa[k]);
            qv[8 + k] = bf2f((unsigned short)qb[k]);
        }
    }

    float acc[16];
#pragma unroll
    for (int k = 0; k < 16; k++) acc[k] = 0.f;
    float lpart = 0.f;

    int cc = end - start;
    int nitm = (cc + 3) >> 2;

    // prologue: predicated load of row j=g (proj + em)
    bf16x8 p0 = {}, p1 = {}, e0 = {}, e1 = {};
    if (g < cc) {
        const unsigned short* row = comb + (size_t)nbr_ids[start + g] * 512 + cb;
        p0 = *reinterpret_cast<const bf16x8*>(row);
        p1 = *reinterpret_cast<const bf16x8*>(row + 8);
        e0 = *reinterpret_cast<const bf16x8*>(row + 256);
        e1 = *reinterpret_cast<const bf16x8*>(row + 264);
    }

    for (int ji = 0; ji < nitm; ji++) {
        // predicated prefetch of next row (proj + em)
        bf16x8 p0n = {}, p1n = {}, e0n = {}, e1n = {};
        int jn = 4 * (ji + 1) + g;
        if (jn < cc) {
            const unsigned short* rown = comb + (size_t)nbr_ids[start + jn] * 512 + cb;
            p0n = *reinterpret_cast<const bf16x8*>(rown);
            p1n = *reinterpret_cast<const bf16x8*>(rown + 8);
            e0n = *reinterpret_cast<const bf16x8*>(rown + 256);
            e1n = *reinterpret_cast<const bf16x8*>(rown + 264);
        }

        // paired-rcp score: 2 exp2 + 1 rcp per element pair
        float sa = 0.f, sb = 0.f;
#pragma unroll
        for (int k = 0; k < 8; k += 2) {
            // pair (p0[k], p1[k])
            float a0 = fexp2(bf2f((unsigned short)p0[k]) + qv[k]) + 1.f;
            float a1 = fexp2(bf2f((unsigned short)p1[k]) + qv[8 + k]) + 1.f;
            float num = vm2[k] * a1;
            num = fmaf(vm2[8 + k], a0, num);
            sa = fmaf(num, __builtin_amdgcn_rcpf(a0 * a1), sa);
            // pair (p0[k+1], p1[k+1])
            float b0 = fexp2(bf2f((unsigned short)p0[k + 1]) + qv[k + 1]) + 1.f;
            float b1 = fexp2(bf2f((unsigned short)p1[k + 1]) + qv[9 + k]) + 1.f;
            float numb = vm2[k + 1] * b1;
            numb = fmaf(vm2[9 + k], b0, numb);
            sb = fmaf(numb, __builtin_amdgcn_rcpf(b0 * b1), sb);
        }
        float s16 = sa + sb + vsum;
        s16 += __shfl_xor(s16, 1);
        s16 += __shfl_xor(s16, 2);
        s16 += __shfl_xor(s16, 4);
        s16 += __shfl_xor(s16, 8);
        float e = fexp2(s16 * LOG2E);
        e = (4 * ji + g < cc) ? e : 0.f;
        lpart += e;
#pragma unroll
        for (int k = 0; k < 8; k++) {
            acc[k] = fmaf(e, bf2f((unsigned short)e0[k]), acc[k]);
            acc[8 + k] = fmaf(e, bf2f((unsigned short)e1[k]), acc[8 + k]);
        }
        p0 = p0n; p1 = p1n; e0 = e0n; e1 = e1n;
    }

    // combine the 4 lane-groups
    lpart += __shfl_xor(lpart, 16);
    lpart += __shfl_xor(lpart, 32);
#pragma unroll
    for (int k = 0; k < 16; k++) {
        acc[k] += __shfl_xor(acc[k], 16);
        acc[k] += __shfl_xor(acc[k], 32);
    }
    float invl = 1.f / lpart;

    // lane (g,li) writes cols cb + 4g .. cb+4g+3 (static selects)
    float4 o;
#pragma unroll
    for (int k = 0; k < 4; k++) {
        float v0 = acc[k], v1 = acc[4 + k], v2 = acc[8 + k], v3 = acc[12 + k];
        float pick = (g == 0) ? v0 : (g == 1) ? v1 : (g == 2) ? v2 : v3;
        if (k == 0) o.x = pick * invl;
        else if (k == 1) o.y = pick * invl;
        else if (k == 2) o.z = pick * invl;
        else o.w = pick * invl;
    }
    *reinterpret_cast<float4*>(orow + cb + 4 * g) = o;
    *reinterpret_cast<float4*>(orow + H + c4) = ssv;
    *reinterpret_cast<float4*>(orow + 2 * H + c4) = rrv;
}

extern "C" void kernel_launch(void* const* d_in, const int* in_sizes, int n_in,
                              void* d_out, int out_size, void* d_ws, size_t ws_size,
                              hipStream_t stream) {
    const int* s = (const int*)d_in[0];
    const int* r = (const int*)d_in[1];
    const int* nbr_ids = (const int*)d_in[2];
    const int* seg_ids = (const int*)d_in[3];
    const float* ent_embeds = (const float*)d_in[4];
    const float* rel_embeds = (const float*)d_in[5];
    const float* W_attn = (const float*)d_in[6];
    const float* b_attn = (const float*)d_in[7];
    const float* v_s = (const float*)d_in[8];
    float* out = (float*)d_out;

    int B = in_sizes[0];
    int N = in_sizes[2];
    int num_ent = in_sizes[4] / H;
    int num_seg = B * SEQ;

    char* ws = (char*)d_ws;
    unsigned short* comb = (unsigned short*)ws;                 // num_ent*512 (proj'|em)
    unsigned short* Wt = comb + (size_t)num_ent * 512;          // H*3H (pre-scaled)
    unsigned short* qpartbf = Wt + (size_t)H * 3 * H;           // B*H (pre-scaled)
    int* seg_start = (int*)(qpartbf + (size_t)B * H);           // num_seg+1

    int nWt = (H * 3 * H + 255) / 256;       // 768
    int nSeg = (N + 255) / 256;              // 1280
    prep_kernel<<<nWt + nSeg, 256, 0, stream>>>(W_attn, Wt, seg_ids, seg_start,
                                                nWt, N, num_seg);

    int nEntBlk = (num_ent + 63) / 64;       // 313
    int nQBlk = B / 64;                      // 32
    gemm_bf16_kernel<<<nEntBlk + nQBlk, 256, 0, stream>>>(
        ent_embeds, s, r, rel_embeds, Wt, b_attn, comb, qpartbf,
        nEntBlk, num_ent, B);

    fused_agg_kernel<<<(num_seg + 1) / 2, 128, 0, stream>>>(
        nbr_ids, seg_start, comb, qpartbf, v_s,
        ent_embeds, rel_embeds, s, r, out, num_seg);
}